// Round 5
// baseline (135.540 us; speedup 1.0000x reference)
//
#include <hip/hip_runtime.h>
#include <math.h>

#define C_CLAMP 10000.0f
#define BYP 0.99f
#define LN2F 0.6931471805599453f

constexpr int NL  = 32;   // leaves
constexpr int NI  = 31;   // internal nodes
constexpr int BLK = 256;

typedef float f4 __attribute__((ext_vector_type(4)));
typedef float f2 __attribute__((ext_vector_type(2)));

// out = exp(log(l) * log(r)) for complex l, r; then nan_to_num + clip.
// Fast path (real-positive operands): exp2(log2(l)*log2(r)*ln2), native trans ops.
// Full complex path behind a WAVE-UNIFORM branch (rarely taken).
template<bool HASIM>
__device__ __forceinline__ void eml_op(float lre, float lim, float rre, float rim,
                                       float& ore, float& oim) {
    bool ok = fminf(lre, rre) > 0.0f;
    if constexpr (HASIM)
        ok = ok & (fmaxf(fabsf(lim), fabsf(rim)) == 0.0f);

    float t = __log2f(lre) * __log2f(rre);
    float e = __builtin_amdgcn_exp2f(t * LN2F);   // +inf -> clipped below
    ore = fminf(e, C_CLAMP);
    oim = 0.0f;

    if (__any(!ok)) {                     // wave-uniform skip
        float a = 0.5f * logf(fmaf(lre, lre, lim * lim));
        float b = atan2f(lim, lre);
        float c = 0.5f * logf(fmaf(rre, rre, rim * rim));
        float d = atan2f(rim, rre);
        float tt = a * c - b * d;
        float th = a * d + b * c;
        float ex = expf(tt);
        float re_ = ex * cosf(th);
        float im_ = ex * sinf(th);
        re_ = __builtin_isnan(re_) ? 0.0f : re_;
        im_ = __builtin_isnan(im_) ? 0.0f : im_;
        re_ = fminf(fmaxf(re_, -C_CLAMP), C_CLAMP);
        im_ = fminf(fmaxf(im_, -C_CLAMP), C_CLAMP);
        if (!ok) { ore = re_; oim = im_; }
    }
}

// g4[node] = (sl_eff, oml_eff, sr_eff, omr_eff); bypass pre-folded to (1,0).
template<int NP, bool HASIM>
__device__ __forceinline__ void do_level(const f4* g4, int node0,
                                         const float* ire, const float* iim,
                                         float* ore, float* oim) {
#pragma unroll
    for (int p = 0; p < NP; ++p) {
        f4 gg = g4[node0 + p];            // one ds_read_b128, broadcast
        float lre = fmaf(gg.y, ire[2 * p],     gg.x);
        float rre = fmaf(gg.w, ire[2 * p + 1], gg.z);
        float lim, rim;
        if constexpr (HASIM) { lim = gg.y * iim[2 * p]; rim = gg.w * iim[2 * p + 1]; }
        else                 { lim = 0.0f; rim = 0.0f; }
        eml_op<HASIM>(lre, lim, rre, rim, ore[p], oim[p]);
    }
}

// PAIRS=true: interleaved (re,im). PAIRS=false: real part only. Plain (cached) stores.
template<bool PAIRS, int NP>
__device__ __forceinline__ void store_lvl(float* __restrict__ dst, long long sb,
                                          const float* re, const float* im) {
    if constexpr (PAIRS) {
        float* p = dst + sb * (2 * NP);
        if constexpr (NP >= 2) {
#pragma unroll
            for (int q = 0; q < NP; q += 2)
                *reinterpret_cast<f4*>(p + 2 * q) = f4{ re[q], im[q], re[q + 1], im[q + 1] };
        } else {
            *reinterpret_cast<f2*>(p) = f2{ re[0], im[0] };
        }
    } else {
        float* p = dst + sb * NP;
        if constexpr (NP >= 4) {
#pragma unroll
            for (int q = 0; q < NP; q += 4)
                *reinterpret_cast<f4*>(p + q) = f4{ re[q], re[q + 1], re[q + 2], re[q + 3] };
        } else if constexpr (NP == 2) {
            *reinterpret_cast<f2*>(p) = f2{ re[0], re[1] };
        } else {
            p[0] = re[0];
        }
    }
}

template<bool PAIRS>
__global__ __launch_bounds__(BLK) void eml_tree_kernel(
    const float* __restrict__ x, const float* __restrict__ y,
    const float* __restrict__ leaf_logits, const float* __restrict__ blend_logits,
    float* __restrict__ o_pred, float* __restrict__ o_leaf, float* __restrict__ o_gate,
    float* __restrict__ o_l1, float* __restrict__ o_l2, float* __restrict__ o_l3,
    float* __restrict__ o_l4, float* __restrict__ o_l5,
    int B, int blocksPerS)
{
    __shared__ f4    w4[NL];        // (w0,w1,w2,0) softmax probs
    __shared__ f4    g4[NI];        // (sl_eff, oml, sr_eff, omr), bypass folded
    __shared__ float graw[NI * 2];  // raw sigmoids for gate_probs output

    const int bid   = blockIdx.x;
    const int s     = bid / blocksPerS;
    const int chunk = bid - s * blocksPerS;
    const int tid   = threadIdx.x;

    if (tid < NL) {
        const float* p = leaf_logits + (s * NL + tid) * 3;
        float a0 = p[0], a1 = p[1], a2 = p[2];
        float m  = fmaxf(a0, fmaxf(a1, a2));
        float e0 = expf(a0 - m), e1 = expf(a1 - m), e2 = expf(a2 - m);
        float inv = 1.0f / (e0 + e1 + e2);
        w4[tid] = f4{ e0 * inv, e1 * inv, e2 * inv, 0.0f };
    } else if (tid >= 64 && tid < 64 + NI) {
        int i = tid - 64;
        const float* p = blend_logits + s * NI * 2 + i * 2;
        float sl = 1.0f / (1.0f + expf(-p[0]));
        float sr = 1.0f / (1.0f + expf(-p[1]));
        graw[i * 2]     = sl;
        graw[i * 2 + 1] = sr;
        bool bl = sl > BYP, br = sr > BYP;
        g4[i] = f4{ bl ? 1.0f : sl, bl ? 0.0f : (1.0f - sl),
                    br ? 1.0f : sr, br ? 0.0f : (1.0f - sr) };
    }
    __syncthreads();

    if (chunk == 0) {
        if (tid < NL * 3)
            o_leaf[s * NL * 3 + tid] = reinterpret_cast<const float*>(w4)[(tid / 3) * 4 + tid % 3];
        if (tid >= 128 && tid < 128 + NI * 2)
            o_gate[s * NI * 2 + (tid - 128)] = graw[tid - 128];
    }

    const int b = chunk * BLK + tid;
    if (b >= B) return;
    const float xv = x[b];
    const float yv = y[b];

    // leaf values: real affine combos (imag = 0)
    float v0[NL];
#pragma unroll
    for (int l = 0; l < NL; ++l) {
        f4 ww = w4[l];
        v0[l] = fmaf(ww.z, yv, fmaf(ww.y, xv, ww.x));
    }

    const long long sb = (long long)s * B + b;

    float r1[16], i1[16];
    do_level<16, false>(g4, 0, v0, nullptr, r1, i1);
    store_lvl<PAIRS, 16>(o_l1, sb, r1, i1);

    float r2[8], i2[8];
    do_level<8, true>(g4, 16, r1, i1, r2, i2);
    store_lvl<PAIRS, 8>(o_l2, sb, r2, i2);

    float r3[4], i3[4];
    do_level<4, true>(g4, 24, r2, i2, r3, i3);
    store_lvl<PAIRS, 4>(o_l3, sb, r3, i3);

    float r4[2], i4[2];
    do_level<2, true>(g4, 28, r3, i3, r4, i4);
    store_lvl<PAIRS, 2>(o_l4, sb, r4, i4);

    float r5[1], i5[1];
    do_level<1, true>(g4, 30, r4, i4, r5, i5);
    store_lvl<PAIRS, 1>(o_l5, sb, r5, i5);
    store_lvl<PAIRS, 1>(o_pred, sb, r5, i5);
}

extern "C" void kernel_launch(void* const* d_in, const int* in_sizes, int n_in,
                              void* d_out, int out_size, void* d_ws, size_t ws_size,
                              hipStream_t stream) {
    const float* x     = (const float*)d_in[0];
    const float* y     = (const float*)d_in[1];
    const float* leaf  = (const float*)d_in[2];
    const float* blend = (const float*)d_in[3];

    const int B = in_sizes[0];
    const int S = in_sizes[2] / (NL * 3);

    float* out = (float*)d_out;
    const long long SB = (long long)S * B;
    const long long size_pairs = SB * 64 + (long long)S * (NL * 3 + NI * 2);

    const int blocksPerS = (B + BLK - 1) / BLK;
    dim3 grid(S * blocksPerS), block(BLK);

    if ((long long)out_size >= size_pairs) {
        // complex64 stored as interleaved float pairs
        float* o_pred = out;                               // SB*2
        float* o_leaf = o_pred + SB * 2;                   // S*96
        float* o_gate = o_leaf + (long long)S * NL * 3;    // S*62
        float* o_l1   = o_gate + (long long)S * NI * 2;    // SB*32
        float* o_l2   = o_l1 + SB * 32;
        float* o_l3   = o_l2 + SB * 16;
        float* o_l4   = o_l3 + SB * 8;
        float* o_l5   = o_l4 + SB * 4;
        hipLaunchKernelGGL((eml_tree_kernel<true>), grid, block, 0, stream,
                           x, y, leaf, blend,
                           o_pred, o_leaf, o_gate, o_l1, o_l2, o_l3, o_l4, o_l5,
                           B, blocksPerS);
    } else {
        // real parts only (harness flattens complex64 outputs as float32 real)
        float* o_pred = out;                               // SB
        float* o_leaf = o_pred + SB;                       // S*96
        float* o_gate = o_leaf + (long long)S * NL * 3;    // S*62
        float* o_l1   = o_gate + (long long)S * NI * 2;    // SB*16
        float* o_l2   = o_l1 + SB * 16;
        float* o_l3   = o_l2 + SB * 8;
        float* o_l4   = o_l3 + SB * 4;
        float* o_l5   = o_l4 + SB * 2;
        hipLaunchKernelGGL((eml_tree_kernel<false>), grid, block, 0, stream,
                           x, y, leaf, blend,
                           o_pred, o_leaf, o_gate, o_l1, o_l2, o_l3, o_l4, o_l5,
                           B, blocksPerS);
    }
}

// Round 6
// 66.504 us; speedup vs baseline: 2.0381x; 2.0381x over previous
//
#include <hip/hip_runtime.h>
#include <math.h>

#define C_CLAMP 10000.0f
#define BYP 0.99f
#define LN2F 0.6931471805599453f

constexpr int NL  = 32;   // leaves
constexpr int NI  = 31;   // internal nodes
constexpr int BLK = 256;

typedef float f4 __attribute__((ext_vector_type(4)));
typedef float f2 __attribute__((ext_vector_type(2)));

// out = exp(log(l) * log(r)) for complex l, r; then nan_to_num + clip.
// Fast path (real-positive operands) unconditional; full complex path behind a
// WAVE-UNIFORM branch (rarely taken).
template<bool HASIM>
__device__ __forceinline__ void eml_op(float lre, float lim, float rre, float rim,
                                       float& ore, float& oim) {
    bool ok = fminf(lre, rre) > 0.0f;
    if constexpr (HASIM)
        ok = ok & (fmaxf(fabsf(lim), fabsf(rim)) == 0.0f);

    float t = __log2f(lre) * __log2f(rre);
    float e = __builtin_amdgcn_exp2f(t * LN2F);   // +inf -> clipped below
    ore = fminf(e, C_CLAMP);
    oim = 0.0f;

    if (__any(!ok)) {                     // wave-uniform skip
        float a = 0.5f * logf(fmaf(lre, lre, lim * lim));
        float b = atan2f(lim, lre);
        float c = 0.5f * logf(fmaf(rre, rre, rim * rim));
        float d = atan2f(rim, rre);
        float tt = a * c - b * d;
        float th = a * d + b * c;
        float ex = expf(tt);
        float re_ = ex * cosf(th);
        float im_ = ex * sinf(th);
        re_ = __builtin_isnan(re_) ? 0.0f : re_;
        im_ = __builtin_isnan(im_) ? 0.0f : im_;
        re_ = fminf(fmaxf(re_, -C_CLAMP), C_CLAMP);
        im_ = fminf(fmaxf(im_, -C_CLAMP), C_CLAMP);
        if (!ok) { ore = re_; oim = im_; }
    }
}

// g4[node] = (sl_eff, oml_eff, sr_eff, omr_eff); bypass pre-folded to (1,0).
template<int NP>
__device__ __forceinline__ void do_level(const f4* g4, int node0,
                                         const float* ire, const float* iim,
                                         float* ore, float* oim) {
#pragma unroll
    for (int p = 0; p < NP; ++p) {
        f4 gg = g4[node0 + p];            // one ds_read_b128, broadcast
        float lre = fmaf(gg.y, ire[2 * p],     gg.x);
        float rre = fmaf(gg.w, ire[2 * p + 1], gg.z);
        float lim = gg.y * iim[2 * p];
        float rim = gg.w * iim[2 * p + 1];
        eml_op<true>(lre, lim, rre, rim, ore[p], oim[p]);
    }
}

// PAIRS=true: interleaved (re,im). PAIRS=false: real part only. Plain (cached) stores.
template<bool PAIRS, int NP>
__device__ __forceinline__ void store_lvl(float* __restrict__ dst, long long sb,
                                          const float* re, const float* im) {
    if constexpr (PAIRS) {
        float* p = dst + sb * (2 * NP);
        if constexpr (NP >= 2) {
#pragma unroll
            for (int q = 0; q < NP; q += 2)
                *reinterpret_cast<f4*>(p + 2 * q) = f4{ re[q], im[q], re[q + 1], im[q + 1] };
        } else {
            *reinterpret_cast<f2*>(p) = f2{ re[0], im[0] };
        }
    } else {
        float* p = dst + sb * NP;
        if constexpr (NP >= 4) {
#pragma unroll
            for (int q = 0; q < NP; q += 4)
                *reinterpret_cast<f4*>(p + q) = f4{ re[q], re[q + 1], re[q + 2], re[q + 3] };
        } else if constexpr (NP == 2) {
            *reinterpret_cast<f2*>(p) = f2{ re[0], re[1] };
        } else {
            p[0] = re[0];
        }
    }
}

template<bool PAIRS>
__global__ __launch_bounds__(BLK, 4) void eml_tree_kernel(
    const float* __restrict__ x, const float* __restrict__ y,
    const float* __restrict__ leaf_logits, const float* __restrict__ blend_logits,
    float* __restrict__ o_pred, float* __restrict__ o_leaf, float* __restrict__ o_gate,
    float* __restrict__ o_l1, float* __restrict__ o_l2, float* __restrict__ o_l3,
    float* __restrict__ o_l4, float* __restrict__ o_l5,
    int B, int blocksPerS)
{
    __shared__ f4    w4[NL];        // (w0,w1,w2,0) softmax probs
    __shared__ f4    g4[NI];        // (sl_eff, oml, sr_eff, omr), bypass folded
    __shared__ float graw[NI * 2];  // raw sigmoids for gate_probs output

    const int bid   = blockIdx.x;
    const int s     = bid / blocksPerS;
    const int chunk = bid - s * blocksPerS;
    const int tid   = threadIdx.x;

    if (tid < NL) {
        const float* p = leaf_logits + (s * NL + tid) * 3;
        float a0 = p[0], a1 = p[1], a2 = p[2];
        float m  = fmaxf(a0, fmaxf(a1, a2));
        float e0 = expf(a0 - m), e1 = expf(a1 - m), e2 = expf(a2 - m);
        float inv = 1.0f / (e0 + e1 + e2);
        w4[tid] = f4{ e0 * inv, e1 * inv, e2 * inv, 0.0f };
    } else if (tid >= 64 && tid < 64 + NI) {
        int i = tid - 64;
        const float* p = blend_logits + s * NI * 2 + i * 2;
        float sl = 1.0f / (1.0f + expf(-p[0]));
        float sr = 1.0f / (1.0f + expf(-p[1]));
        graw[i * 2]     = sl;
        graw[i * 2 + 1] = sr;
        bool bl = sl > BYP, br = sr > BYP;
        g4[i] = f4{ bl ? 1.0f : sl, bl ? 0.0f : (1.0f - sl),
                    br ? 1.0f : sr, br ? 0.0f : (1.0f - sr) };
    }
    __syncthreads();

    if (chunk == 0) {
        if (tid < NL * 3)
            o_leaf[s * NL * 3 + tid] = reinterpret_cast<const float*>(w4)[(tid / 3) * 4 + tid % 3];
        if (tid >= 128 && tid < 128 + NI * 2)
            o_gate[s * NI * 2 + (tid - 128)] = graw[tid - 128];
    }

    const int b = chunk * BLK + tid;
    if (b >= B) return;
    const float xv = x[b];
    const float yv = y[b];

    const long long sb = (long long)s * B + b;

    // Level 1 with leaf evaluation fused in (kills the v0[32] live range):
    float r1[16], i1[16];
#pragma unroll
    for (int p = 0; p < 16; ++p) {
        f4 gg = g4[p];
        f4 wa = w4[2 * p];
        f4 wb = w4[2 * p + 1];
        float La = fmaf(wa.z, yv, fmaf(wa.y, xv, wa.x));
        float Lb = fmaf(wb.z, yv, fmaf(wb.y, xv, wb.x));
        float lre = fmaf(gg.y, La, gg.x);
        float rre = fmaf(gg.w, Lb, gg.z);
        eml_op<false>(lre, 0.0f, rre, 0.0f, r1[p], i1[p]);
    }
    store_lvl<PAIRS, 16>(o_l1, sb, r1, i1);

    float r2[8], i2[8];
    do_level<8>(g4, 16, r1, i1, r2, i2);
    store_lvl<PAIRS, 8>(o_l2, sb, r2, i2);

    float r3[4], i3[4];
    do_level<4>(g4, 24, r2, i2, r3, i3);
    store_lvl<PAIRS, 4>(o_l3, sb, r3, i3);

    float r4[2], i4[2];
    do_level<2>(g4, 28, r3, i3, r4, i4);
    store_lvl<PAIRS, 2>(o_l4, sb, r4, i4);

    float r5[1], i5[1];
    do_level<1>(g4, 30, r4, i4, r5, i5);
    store_lvl<PAIRS, 1>(o_l5, sb, r5, i5);
    store_lvl<PAIRS, 1>(o_pred, sb, r5, i5);
}

extern "C" void kernel_launch(void* const* d_in, const int* in_sizes, int n_in,
                              void* d_out, int out_size, void* d_ws, size_t ws_size,
                              hipStream_t stream) {
    const float* x     = (const float*)d_in[0];
    const float* y     = (const float*)d_in[1];
    const float* leaf  = (const float*)d_in[2];
    const float* blend = (const float*)d_in[3];

    const int B = in_sizes[0];
    const int S = in_sizes[2] / (NL * 3);

    float* out = (float*)d_out;
    const long long SB = (long long)S * B;
    const long long size_pairs = SB * 64 + (long long)S * (NL * 3 + NI * 2);

    const int blocksPerS = (B + BLK - 1) / BLK;
    dim3 grid(S * blocksPerS), block(BLK);

    if ((long long)out_size >= size_pairs) {
        // complex64 stored as interleaved float pairs
        float* o_pred = out;                               // SB*2
        float* o_leaf = o_pred + SB * 2;                   // S*96
        float* o_gate = o_leaf + (long long)S * NL * 3;    // S*62
        float* o_l1   = o_gate + (long long)S * NI * 2;    // SB*32
        float* o_l2   = o_l1 + SB * 32;
        float* o_l3   = o_l2 + SB * 16;
        float* o_l4   = o_l3 + SB * 8;
        float* o_l5   = o_l4 + SB * 4;
        hipLaunchKernelGGL((eml_tree_kernel<true>), grid, block, 0, stream,
                           x, y, leaf, blend,
                           o_pred, o_leaf, o_gate, o_l1, o_l2, o_l3, o_l4, o_l5,
                           B, blocksPerS);
    } else {
        // real parts only (harness flattens complex64 outputs as float32 real)
        float* o_pred = out;                               // SB
        float* o_leaf = o_pred + SB;                       // S*96
        float* o_gate = o_leaf + (long long)S * NL * 3;    // S*62
        float* o_l1   = o_gate + (long long)S * NI * 2;    // SB*16
        float* o_l2   = o_l1 + SB * 16;
        float* o_l3   = o_l2 + SB * 8;
        float* o_l4   = o_l3 + SB * 4;
        float* o_l5   = o_l4 + SB * 2;
        hipLaunchKernelGGL((eml_tree_kernel<false>), grid, block, 0, stream,
                           x, y, leaf, blend,
                           o_pred, o_leaf, o_gate, o_l1, o_l2, o_l3, o_l4, o_l5,
                           B, blocksPerS);
    }
}